// Round 1
// 174.257 us; speedup vs baseline: 1.0206x; 1.0206x over previous
//
#include <hip/hip_runtime.h>

#define NUM 16
#define TPB 256
#define TILES 2
#define TRACKS_PER_TILE (TPB / 4)                   // 64 tracks per tile per block
#define TRACKS_PER_BLOCK (TRACKS_PER_TILE * TILES)  // 128 tracks per block

// Round-7 structure: 4-lane cooperative rows. Lane l handles row (l&3) of track
// (l>>2). P/rP are one float4 per lane, wave-contiguous (1 KB per dwordx4
// instruction) -> NO LDS, NO barriers, no bank conflicts. Row-wise Kalman
// algebra needs only quad shuffles:
//   Q_r   = P_r + (r<2 ? P_{r^2} : 0)            (shfl_xor 2)
//   pP_r  : intra-lane column adds
//   S,K,y : broadcast pP rows 0,1 + pred rows 0,1 (shfl within width-4)
// Two tracks per thread, all loads issued before compute (double MLP).
// __launch_bounds__(256,8): force VGPR<=64 -> 8 waves/SIMD (vs 58% occ before).
__global__ __launch_bounds__(TPB, 8) void kf_update_kernel(
    const float* __restrict__ value,   // (B, 32)
    const float* __restrict__ vel,     // (B, 32)
    const float* __restrict__ Pin,     // (B, 16, 4, 4)
    const float* __restrict__ obs,     // (B, 32)
    const int*   __restrict__ lm,      // (B, 16)
    const int*   __restrict__ mask,    // (B, 16)
    float* __restrict__ out,           // rv(B*32) | rm(B*16) | rvel(B*32) | rP(B*256)
    int Bn)
{
    const int tid = threadIdx.x;
    const int r   = tid & 3;    // row of the 4x4 this lane owns
    const int sub = tid >> 2;   // track slot within block (0..63)
    const int total = Bn * NUM;

    float* __restrict__ rv_out   = out;
    float* __restrict__ rm_out   = out + (size_t)Bn * 32;
    float* __restrict__ rvel_out = out + (size_t)Bn * 48;
    float* __restrict__ rP_out   = out + (size_t)Bn * 80;

    const int base = blockIdx.x * TRACKS_PER_BLOCK + sub;

    int    t[TILES];
    bool   act[TILES];
    float4 Pr[TILES];
    float2 v2[TILES], u2[TILES], o2[TILES];
    int    lv[TILES], mv[TILES];

    // ---- issue ALL loads first (both tiles) for max memory-level parallelism ----
    #pragma unroll
    for (int k = 0; k < TILES; ++k) {
        t[k]   = base + k * TRACKS_PER_TILE;
        act[k] = t[k] < total;
        const int tc = act[k] ? t[k] : 0;
        // P row r of track tc: float4 index 4*tc + r == wave-contiguous (== tid)
        Pr[k] = reinterpret_cast<const float4*>(Pin)[(size_t)tc * 4 + r];
        v2[k] = reinterpret_cast<const float2*>(value)[tc];
        u2[k] = reinterpret_cast<const float2*>(vel)[tc];
        o2[k] = reinterpret_cast<const float2*>(obs)[tc];
        lv[k] = lm[tc];
        mv[k] = mask[tc];
    }

    // ---- compute + store per tile ----
    #pragma unroll
    for (int k = 0; k < TILES; ++k) {
        // pred = F @ [vx,vy,ux,uy]; lane owns component r
        const float pr = (r == 0) ? (v2[k].x + u2[k].x)
                       : (r == 1) ? (v2[k].y + u2[k].y)
                       : (r == 2) ? u2[k].x
                                  : u2[k].y;

        // Q = F @ P : rows 0,1 add rows 2,3 (quad shuffle xor 2)
        float q0 = Pr[k].x, q1 = Pr[k].y, q2 = Pr[k].z, q3 = Pr[k].w;
        const float x0 = __shfl_xor(q0, 2);
        const float x1 = __shfl_xor(q1, 2);
        const float x2 = __shfl_xor(q2, 2);
        const float x3 = __shfl_xor(q3, 2);
        if (r < 2) { q0 += x0; q1 += x1; q2 += x2; q3 += x3; }

        // pP = Q @ F^T : per-row column adds (intra-lane)
        const float a0 = q0 + q2;
        const float a1 = q1 + q3;
        const float a2 = q2;
        const float a3 = q3;

        // broadcast pP rows 0 and 1 to the quad
        const float r00 = __shfl(a0, 0, 4), r01 = __shfl(a1, 0, 4);
        const float r02 = __shfl(a2, 0, 4), r03 = __shfl(a3, 0, 4);
        const float r10 = __shfl(a0, 1, 4), r11 = __shfl(a1, 1, 4);
        const float r12 = __shfl(a2, 1, 4), r13 = __shfl(a3, 1, 4);

        // S = pP[:2,:2] + 1e-5 I ; closed-form inverse folded into K
        const float S00 = r00 + 1e-5f;
        const float S01 = r01;
        const float S10 = r10;
        const float S11 = r11 + 1e-5f;
        const float rdet = 1.0f / (S00 * S11 - S01 * S10);

        // K row r: K0 = (pP[r][0]*S11 - pP[r][1]*S10)/det, K1 analogous
        const float K0 = (a0 * S11 - a1 * S10) * rdet;
        const float K1 = (a1 * S00 - a0 * S01) * rdet;

        // innovation needs pred rows 0,1
        const float p0 = __shfl(pr, 0, 4);
        const float p1 = __shfl(pr, 1, 4);
        const float y0 = o2[k].x - p0;
        const float y1 = o2[k].y - p1;
        const float updr = pr + K0 * y0 + K1 * y1;

        // Pn row r = pP_r - (K0 * pP_row0 + K1 * pP_row1)
        const float Pn0 = a0 - (K0 * r00 + K1 * r10);
        const float Pn1 = a1 - (K0 * r01 + K1 * r11);
        const float Pn2 = a2 - (K0 * r02 + K1 * r12);
        const float Pn3 = a3 - (K0 * r03 + K1 * r13);

        // condition table
        const int  l  = lv[k], m = mv[k];
        const bool c1  = (l == 0) && (m == 0);
        const bool c3  = (l != 0) && (m == 0);
        const bool c4  = (l != 0) && (m != 0);
        const bool c3a = c3 && (l <= 5);

        // rP row r: c1 -> diag(1,1,10,10) row, c3a -> pP, c4 -> Pn, else 0
        const float dv = (r < 2) ? 1.0f : 10.0f;
        float4 e;
        e.x = c1 ? ((r == 0) ? dv : 0.0f) : (c3a ? a0 : (c4 ? Pn0 : 0.0f));
        e.y = c1 ? ((r == 1) ? dv : 0.0f) : (c3a ? a1 : (c4 ? Pn1 : 0.0f));
        e.z = c1 ? ((r == 2) ? dv : 0.0f) : (c3a ? a2 : (c4 ? Pn2 : 0.0f));
        e.w = c1 ? ((r == 3) ? dv : 0.0f) : (c3a ? a3 : (c4 ? Pn3 : 0.0f));
        if (act[k])
            reinterpret_cast<float4*>(rP_out)[(size_t)t[k] * 4 + r] = e;

        // rv (rows 0,1) and rvel (rows 2,3): each lane stores exactly the
        // component it owns natively -> one store instr, two dense 128B spans
        float  sval;
        float* sp;
        if (r < 2) {
            const float oc = (r == 0) ? o2[k].x : o2[k].y;
            sval = c4 ? updr : (c3 ? pr : oc);
            sp   = rv_out + (size_t)t[k] * 2 + r;
        } else {
            sval = c4 ? updr : (c3a ? pr : 0.0f);
            sp   = rvel_out + (size_t)t[k] * 2 + (r - 2);
        }
        if (act[k]) *sp = sval;

        // rm: (c2|c4) == (m != 0) -> 1, else c3a -> l+1, else 0
        const float rmv = (m != 0) ? 1.0f : (c3a ? (float)(l + 1) : 0.0f);
        if (act[k] && r == 0) rm_out[t[k]] = rmv;
    }
}

extern "C" void kernel_launch(void* const* d_in, const int* in_sizes, int n_in,
                              void* d_out, int out_size, void* d_ws, size_t ws_size,
                              hipStream_t stream) {
    const float* value = (const float*)d_in[0];
    const float* vel   = (const float*)d_in[1];
    const float* P     = (const float*)d_in[2];
    const float* obs   = (const float*)d_in[3];
    const int*   lm    = (const int*)d_in[4];
    const int*   mask  = (const int*)d_in[5];

    const int Bn     = in_sizes[0] / (2 * NUM);   // value is (B, 2*NUM)
    const int total  = Bn * NUM;
    const int blocks = (total + TRACKS_PER_BLOCK - 1) / TRACKS_PER_BLOCK;

    kf_update_kernel<<<blocks, TPB, 0, stream>>>(
        value, vel, P, obs, lm, mask, (float*)d_out, Bn);
}